// Round 2
// baseline (847.011 us; speedup 1.0000x reference)
//
#include <hip/hip_runtime.h>
#include <hip/hip_bf16.h>

// SoftmaxPooling on MI355X (gfx950) — R2: occupancy-focused restructure.
//   scores = tanh(h @ W1 + b1) @ w2 ; per-track(10) softmax ; pooled = w-avg of h
//
// Changes vs R1 (which was latency-bound at 23% occupancy, 1 block/CU, LDS 137 KB):
//  - W1^T staged in 4 column-chunks of 64 (LDS 34.4 KB -> 4 blocks/CU by LDS);
//    score partials are additive across chunks so only sc regs persist.
//  - 320-thread blocks, 16 tracks = 10 MFMA strips, exactly 2 strips/wave
//    (balanced; A-frags 64 VGPRs).
//  - W1 pre-converted to bf16 LDS-image in d_ws by a tiny kernel; Phase A is a
//    pure global_load_lds_dwordx4 async copy (no VALU, no LDS-write conflicts).

typedef __attribute__((ext_vector_type(8))) short short8;  // 8 bf16 (4 VGPRs) MFMA A/B frag
typedef __attribute__((ext_vector_type(4))) float f32x4;   // MFMA C/D frag

#define LATENT      256
#define HPT         10
#define TPB_TRACKS  16
#define ROWS_PB     (TPB_TRACKS * HPT)   // 160 rows
#define STRIPS_PB   (ROWS_PB / 16)       // 10 strips
#define WAVES       5
#define THREADS     (WAVES * 64)         // 320
#define NCHUNK      4
#define CHUNK_N     64                   // W1^T rows (output cols) per chunk
#define W1_STRIDE   264                  // shorts per row: 256 + 8 pad (16B aligned)
#define CHUNK_BYTES (CHUNK_N * W1_STRIDE * 2)   // 33792
#define IMG_BYTES   (256 * W1_STRIDE * 2)       // 135168
#define LOG2E       1.44269504088896f

__device__ __forceinline__ short bf16_rne(float x) {
    unsigned u = __float_as_uint(x);
    u += 0x7FFFu + ((u >> 16) & 1u);
    return (short)(u >> 16);
}

__device__ __forceinline__ float tanh_fast(float x) {
    float e = __builtin_amdgcn_exp2f(x * (2.0f * LOG2E));
    return 1.0f - 2.0f * __builtin_amdgcn_rcpf(e + 1.0f);
}

__device__ __forceinline__ void async_copy16(const void* g, void* l) {
    __builtin_amdgcn_global_load_lds(
        (const __attribute__((address_space(1))) unsigned int*)g,
        (__attribute__((address_space(3))) unsigned int*)l, 16, 0, 0);
}

// ---- Kernel 0: W1 (fp32 [k][n]) -> bf16 LDS image W1^T [n][k] with padded stride ----
__global__ __launch_bounds__(256)
void convert_w1_kernel(const float* __restrict__ W1, short* __restrict__ img) {
    int idx = blockIdx.x * 256 + threadIdx.x;    // 132*256 = 33792 = 256 rows * 132 pairs
    int p = idx >> 8;                            // pair index 0..131
    int n = idx & 255;                           // coalesced W1 reads across lanes
    short2 v; v.x = 0; v.y = 0;
    if (p < 128) {
        int k = p * 2;
        v.x = bf16_rne(W1[(size_t)k * 256 + n]);
        v.y = bf16_rne(W1[(size_t)(k + 1) * 256 + n]);
    }
    *(short2*)&img[(size_t)n * W1_STRIDE + p * 2] = v;
}

// ---- Kernel 1: fused scores + softmax + pooling ----
__global__ __launch_bounds__(THREADS, 4)
void softmax_pool_kernel(const float* __restrict__ h,
                         const float* __restrict__ W1,
                         const float* __restrict__ b1,
                         const float* __restrict__ w2,
                         const short* __restrict__ img,
                         float* __restrict__ out,
                         int n_hits, int num_tracks, int use_ws)
{
    __shared__ __align__(16) short w1t[CHUNK_N * W1_STRIDE];   // 33792 B
    __shared__ float sc_lds[ROWS_PB];                          // 640 B

    const int tid  = threadIdx.x;
    const int wave = tid >> 6;
    const int lane = tid & 63;
    const int q    = lane >> 4;   // quad 0..3
    const int c    = lane & 15;
    const int blk  = blockIdx.x;

    // ---------------- A-fragments: 2 strips per wave, full K in registers ----------------
    // a[st][kt] holds h[row = strip*16 + c][k = kt*32 + q*8 + j], j=0..7, as bf16
    short8 a[2][8];
    #pragma unroll
    for (int st = 0; st < 2; ++st) {
        const int strip = wave + st * WAVES;
        size_t row = (size_t)blk * ROWS_PB + (size_t)strip * 16 + c;
        if (row >= (size_t)n_hits) row = n_hits - 1;   // grid divides exactly; safety only
        const float* hrow = h + row * LATENT + q * 8;
        #pragma unroll
        for (int kt = 0; kt < 8; ++kt) {
            float4 f0 = *(const float4*)(hrow + kt * 32);
            float4 f1 = *(const float4*)(hrow + kt * 32 + 4);
            short8 v;
            v[0] = bf16_rne(f0.x); v[1] = bf16_rne(f0.y);
            v[2] = bf16_rne(f0.z); v[3] = bf16_rne(f0.w);
            v[4] = bf16_rne(f1.x); v[5] = bf16_rne(f1.y);
            v[6] = bf16_rne(f1.z); v[7] = bf16_rne(f1.w);
            a[st][kt] = v;
        }
    }

    f32x4 zero4 = {0.0f, 0.0f, 0.0f, 0.0f};
    f32x4 sc0 = zero4, sc1 = zero4;   // per-strip score partials (additive across chunks)

    // ---------------- column-chunk loop: stage 64 cols of W1^T, MFMA, fold tanh·w2 -------
    for (int chunk = 0; chunk < NCHUNK; ++chunk) {
        __syncthreads();   // previous chunk's LDS reads complete before overwrite
        if (use_ws) {
            const char* src = (const char*)img + (size_t)chunk * CHUNK_BYTES;
            char* dst = (char*)w1t;
            for (int off = wave * 1024; off < CHUNK_BYTES; off += WAVES * 1024)
                async_copy16(src + off + lane * 16, dst + off);
        } else {
            // fallback: convert W1 directly (ws too small)
            for (int idx = tid; idx < CHUNK_N * 132; idx += THREADS) {
                int nl = idx & (CHUNK_N - 1);
                int p  = idx >> 6;          // 0..131
                short2 v; v.x = 0; v.y = 0;
                if (p < 128) {
                    int k = p * 2;
                    int n = chunk * CHUNK_N + nl;
                    v.x = bf16_rne(W1[(size_t)k * 256 + n]);
                    v.y = bf16_rne(W1[(size_t)(k + 1) * 256 + n]);
                }
                *(short2*)&w1t[nl * W1_STRIDE + p * 2] = v;
            }
        }
        __syncthreads();   // drains global_load_lds (vmcnt) + LDS writes

        #pragma unroll
        for (int ct = 0; ct < 4; ++ct) {
            const int n = chunk * CHUNK_N + ct * 16 + c;
            const short* bbase = &w1t[(ct * 16 + c) * W1_STRIDE + q * 8];
            f32x4 acc0 = zero4, acc1 = zero4;
            #pragma unroll
            for (int kt = 0; kt < 8; ++kt) {
                short8 bf = *(const short8*)(bbase + kt * 32);   // ds_read_b128
                acc0 = __builtin_amdgcn_mfma_f32_16x16x32_bf16(a[0][kt], bf, acc0, 0, 0, 0);
                acc1 = __builtin_amdgcn_mfma_f32_16x16x32_bf16(a[1][kt], bf, acc1, 0, 0, 0);
            }
            // acc[r] = u[row = strip*16 + q*4 + r][n]; fold tanh + dot(w2)
            float b1n = b1[n];
            float w2n = w2[n];
            #pragma unroll
            for (int r = 0; r < 4; ++r) {
                sc0[r] += w2n * tanh_fast(acc0[r] + b1n);
                sc1[r] += w2n * tanh_fast(acc1[r] + b1n);
            }
        }
    }

    // ---------------- reduce partials across the 16 column-lanes ----------------
    #pragma unroll
    for (int r = 0; r < 4; ++r) {
        float v0 = sc0[r], v1 = sc1[r];
        v0 += __shfl_xor(v0, 1); v0 += __shfl_xor(v0, 2);
        v0 += __shfl_xor(v0, 4); v0 += __shfl_xor(v0, 8);
        v1 += __shfl_xor(v1, 1); v1 += __shfl_xor(v1, 2);
        v1 += __shfl_xor(v1, 4); v1 += __shfl_xor(v1, 8);
        sc0[r] = v0; sc1[r] = v1;
    }
    if (c == 0) {
        float4 o0; o0.x = sc0[0]; o0.y = sc0[1]; o0.z = sc0[2]; o0.w = sc0[3];
        *(float4*)&sc_lds[wave * 16 + q * 4] = o0;
        float4 o1; o1.x = sc1[0]; o1.y = sc1[1]; o1.z = sc1[2]; o1.w = sc1[3];
        *(float4*)&sc_lds[(wave + WAVES) * 16 + q * 4] = o1;
    }
    __syncthreads();

    // ---------------- per-track softmax (scores -> weights, in place) ----------------
    if (tid < TPB_TRACKS) {
        float s[HPT];
        float m = -1e30f;
        #pragma unroll
        for (int i = 0; i < HPT; ++i) {
            s[i] = sc_lds[tid * HPT + i];
            m = fmaxf(m, s[i]);
        }
        float sum = 0.0f;
        #pragma unroll
        for (int i = 0; i < HPT; ++i) {
            s[i] = __builtin_amdgcn_exp2f((s[i] - m) * LOG2E);
            sum += s[i];
        }
        float inv = __builtin_amdgcn_rcpf(sum);
        #pragma unroll
        for (int i = 0; i < HPT; ++i)
            sc_lds[tid * HPT + i] = s[i] * inv;
    }
    __syncthreads();

    // ---------------- weighted pooling (h rows re-read; served by L2) ----------------
    for (int t = wave; t < TPB_TRACKS; t += WAVES) {
        int tg = blk * TPB_TRACKS + t;
        if (tg >= num_tracks) continue;
        const float* hb = h + (size_t)tg * HPT * LATENT + lane * 4;
        float4 acc = {0.0f, 0.0f, 0.0f, 0.0f};
        #pragma unroll
        for (int i = 0; i < HPT; ++i) {
            float wi = sc_lds[t * HPT + i];
            float4 v = *(const float4*)(hb + (size_t)i * LATENT);
            acc.x += wi * v.x;
            acc.y += wi * v.y;
            acc.z += wi * v.z;
            acc.w += wi * v.w;
        }
        *(float4*)(out + (size_t)tg * LATENT + lane * 4) = acc;
    }
}

extern "C" void kernel_launch(void* const* d_in, const int* in_sizes, int n_in,
                              void* d_out, int out_size, void* d_ws, size_t ws_size,
                              hipStream_t stream) {
    const float* h  = (const float*)d_in[0];
    const float* W1 = (const float*)d_in[1];
    const float* b1 = (const float*)d_in[2];
    const float* w2 = (const float*)d_in[3];
    float* out = (float*)d_out;

    int n_hits     = in_sizes[0] / LATENT;    // 500000
    int num_tracks = out_size / LATENT;       // 50000
    int blocks     = (num_tracks + TPB_TRACKS - 1) / TPB_TRACKS;   // 3125

    int use_ws = (ws_size >= (size_t)IMG_BYTES) ? 1 : 0;
    short* img = (short*)d_ws;

    if (use_ws)
        convert_w1_kernel<<<132, 256, 0, stream>>>(W1, img);

    softmax_pool_kernel<<<blocks, THREADS, 0, stream>>>(h, W1, b1, w2, img, out,
                                                        n_hits, num_tracks, use_ws);
}